// Round 1
// 307.947 us; speedup vs baseline: 1.0548x; 1.0548x over previous
//
#include <hip/hip_runtime.h>
#include <hip/hip_fp16.h>

#define D 64
#define NBUK 391      // ceil(100096/256) buckets of 256 nodes (key >> 8)
#define NBIN (2 * NBUK)
#define CHUNK 8192    // edges per block in phase1/phase2 (196 blocks)
#define PBSTRIDE 256  // padded blocks-per-bin stride in transposed per_block

// ---- async global->LDS helpers (size must be literal) ----
__device__ __forceinline__ void llds16(const void* g, const void* l) {
    __builtin_amdgcn_global_load_lds((const __attribute__((address_space(1))) void*)g,
                                     (__attribute__((address_space(3))) void*)l, 16, 0, 0);
}
__device__ __forceinline__ void llds4(const void* g, const void* l) {
    __builtin_amdgcn_global_load_lds((const __attribute__((address_space(1))) void*)g,
                                     (__attribute__((address_space(3))) void*)l, 4, 0, 0);
}

// ---- phase1: per-block coarse histograms, written bin-major (transposed) ----
__global__ __launch_bounds__(256) void phase1_kernel(const int* __restrict__ src,
                                                     const int* __restrict__ dst,
                                                     int* __restrict__ per_block, int E) {
    __shared__ int h[NBIN];
    int tid = (int)threadIdx.x;
    for (int j = tid; j < NBIN; j += 256) h[j] = 0;
    __syncthreads();
    int base = blockIdx.x * CHUNK;
    int cnt = min(CHUNK, E - base);
    for (int k = tid * 4; k < cnt; k += 1024) {
        if (k + 3 < cnt) {
            int4 d4 = *(const int4*)(dst + base + k);
            int4 s4 = *(const int4*)(src + base + k);
            atomicAdd(&h[d4.x >> 8], 1); atomicAdd(&h[d4.y >> 8], 1);
            atomicAdd(&h[d4.z >> 8], 1); atomicAdd(&h[d4.w >> 8], 1);
            atomicAdd(&h[NBUK + (s4.x >> 8)], 1); atomicAdd(&h[NBUK + (s4.y >> 8)], 1);
            atomicAdd(&h[NBUK + (s4.z >> 8)], 1); atomicAdd(&h[NBUK + (s4.w >> 8)], 1);
        } else {
            int kend = (k + 4 < cnt) ? k + 4 : cnt;
            for (int t = k; t < kend; ++t) {
                atomicAdd(&h[dst[base + t] >> 8], 1);
                atomicAdd(&h[NBUK + (src[base + t] >> 8)], 1);
            }
        }
    }
    __syncthreads();
    // writes columns 0..gridDim-1 of every bin row; pad columns are never read
    for (int j = tid; j < NBIN; j += 256) per_block[j * PBSTRIDE + blockIdx.x] = h[j];
}

// ---- scanA (transposed): one wave per bin scans its nblk contiguous counts ----
// Pad columns are NOT zeroed anymore (memset removed) -> guard the reads.
__global__ __launch_bounds__(256) void scanA_kernel(int* __restrict__ per_block,
                                                    int* __restrict__ total, int nblk) {
    int wv = (int)threadIdx.x >> 6;
    int lane = (int)threadIdx.x & 63;
    int j = blockIdx.x * 4 + wv;
    if (j >= NBIN) return;
    int* pb = per_block + (size_t)j * PBSTRIDE;
    int idx = lane * 4;
    int4 v = make_int4(0, 0, 0, 0);
    if (idx + 3 < nblk) {
        v = *(const int4*)(pb + idx);
    } else if (idx < nblk) {
        v.x = pb[idx];
        if (idx + 1 < nblk) v.y = pb[idx + 1];
        if (idx + 2 < nblk) v.z = pb[idx + 2];
    }
    int s1 = v.x + v.y, s2 = s1 + v.z, s3 = s2 + v.w;
    int x = s3;
#pragma unroll
    for (int d = 1; d < 64; d <<= 1) {
        int t = __shfl_up(x, d);
        if (lane >= d) x += t;
    }
    int excl = x - s3;
    int4 r = make_int4(excl, excl + v.x, excl + s1, excl + s2);
    *(int4*)(pb + idx) = r;   // pad-column writes land in allocated pad, never read
    if (lane == 63) total[j] = x;
}

// ---- scanB: exclusive-scan bucket totals for dst and src halves; zero msum ----
__global__ __launch_bounds__(512) void scanB_kernel(const int* __restrict__ total,
                                                    int* __restrict__ cb_dst,
                                                    int* __restrict__ cb_src,
                                                    float* __restrict__ msum) {
    __shared__ int s[512];
    int tid = (int)threadIdx.x;
    if (tid < D) msum[tid] = 0.0f;   // runs long before fused mode-1 atomics
    for (int half = 0; half < 2; ++half) {
        int v = (tid < NBUK) ? total[half * NBUK + tid] : 0;
        s[tid] = v;
        __syncthreads();
        for (int off = 1; off < 512; off <<= 1) {
            int t = (tid >= off) ? s[tid - off] : 0;
            __syncthreads();
            s[tid] += t;
            __syncthreads();
        }
        int* cb = half ? cb_src : cb_dst;
        if (tid < NBUK) cb[tid] = s[tid] - v;
        if (tid == NBUK - 1) cb[NBUK] = s[tid];
        __syncthreads();
    }
}

// ---- phase2: scatter edges to bucket order via LDS cursors ----
__global__ __launch_bounds__(256) void phase2_kernel(const int* __restrict__ src,
                                                     const int* __restrict__ dst,
                                                     const int* __restrict__ per_block,
                                                     const int* __restrict__ cb_dst,
                                                     const int* __restrict__ cb_src,
                                                     int* __restrict__ pairs,
                                                     unsigned char* __restrict__ skeys, int E) {
    __shared__ int lcur[NBIN];
    int tid = (int)threadIdx.x;
    for (int j = tid; j < NBIN; j += 256)
        lcur[j] = per_block[(size_t)j * PBSTRIDE + blockIdx.x] +
                  (j < NBUK ? cb_dst[j] : cb_src[j - NBUK]);
    __syncthreads();
    int base = blockIdx.x * CHUNK;
    int cnt = min(CHUNK, E - base);
    for (int k = tid * 4; k < cnt; k += 1024) {
        if (k + 3 < cnt) {
            int4 d4 = *(const int4*)(dst + base + k);
            int4 s4 = *(const int4*)(src + base + k);
            int p;
            p = atomicAdd(&lcur[d4.x >> 8], 1); pairs[p] = (s4.x << 8) | (d4.x & 255);
            p = atomicAdd(&lcur[d4.y >> 8], 1); pairs[p] = (s4.y << 8) | (d4.y & 255);
            p = atomicAdd(&lcur[d4.z >> 8], 1); pairs[p] = (s4.z << 8) | (d4.z & 255);
            p = atomicAdd(&lcur[d4.w >> 8], 1); pairs[p] = (s4.w << 8) | (d4.w & 255);
            p = atomicAdd(&lcur[NBUK + (s4.x >> 8)], 1); skeys[p] = (unsigned char)(s4.x & 255);
            p = atomicAdd(&lcur[NBUK + (s4.y >> 8)], 1); skeys[p] = (unsigned char)(s4.y & 255);
            p = atomicAdd(&lcur[NBUK + (s4.z >> 8)], 1); skeys[p] = (unsigned char)(s4.z & 255);
            p = atomicAdd(&lcur[NBUK + (s4.w >> 8)], 1); skeys[p] = (unsigned char)(s4.w & 255);
        } else {
            int kend = (k + 4 < cnt) ? k + 4 : cnt;
            for (int t = k; t < kend; ++t) {
                int dv = dst[base + t], sv = src[base + t];
                int p = atomicAdd(&lcur[dv >> 8], 1);
                pairs[p] = (sv << 8) | (dv & 255);
                p = atomicAdd(&lcur[NBUK + (sv >> 8)], 1);
                skeys[p] = (unsigned char)(sv & 255);
            }
        }
    }
}

// ---- finalize: per bucket, dinv from src-keys; row_ptr + col from dst-pairs;
//      ALSO prescale this bucket's 256 feature rows to fp16 (fused prescale) ----
__global__ __launch_bounds__(256) void finalize_csr_kernel(const int* __restrict__ pairs,
                                                           const unsigned char* __restrict__ skeys,
                                                           const int* __restrict__ cb_dst,
                                                           const int* __restrict__ cb_src,
                                                           const float* __restrict__ feat,
                                                           int* __restrict__ row_ptr,
                                                           int* __restrict__ col,
                                                           float* __restrict__ dinv,
                                                           __half* __restrict__ hs, int N) {
    __shared__ int fine[256];
    __shared__ int lcur[256];
    __shared__ float dsh[256];
    __shared__ int wtot[4], wexcl[4];
    int b = (int)blockIdx.x;
    int tid = (int)threadIdx.x, lane = tid & 63, wv = tid >> 6;
    int g = b * 256 + tid;

    // out-degree -> dinv
    fine[tid] = 0;
    __syncthreads();
    int sb0 = cb_src[b], sb1 = cb_src[b + 1];
    for (int i = sb0 + tid; i < sb1; i += 256) atomicAdd(&fine[skeys[i]], 1);
    __syncthreads();
    float dv_ = 1.0f / fmaxf((float)fine[tid], 1.0f);
    dsh[tid] = dv_;
    if (g < N) dinv[g] = dv_;
    __syncthreads();

    // prescale this bucket's rows: hs[node][:] = half(feat[node][:] * dinv[node])
    {
        int q = tid & 7;                 // 8 threads per row, 8 floats each
        int rbase = tid >> 3;            // 32 rows per pass
        for (int p = 0; p < 8; ++p) {
            int r = p * 32 + rbase;
            int node = b * 256 + r;
            if (node < N) {
                float sc = dsh[r];
                const float4* f = (const float4*)(feat + (size_t)node * D + q * 8);
                float4 v0 = f[0], v1 = f[1];
                __half2 h[4];
                h[0] = __floats2half2_rn(v0.x * sc, v0.y * sc);
                h[1] = __floats2half2_rn(v0.z * sc, v0.w * sc);
                h[2] = __floats2half2_rn(v1.x * sc, v1.y * sc);
                h[3] = __floats2half2_rn(v1.z * sc, v1.w * sc);
                *(float4*)(hs + (size_t)node * D + q * 8) = *(float4*)h;
            }
        }
    }
    __syncthreads();

    // in-degree fine hist
    fine[tid] = 0;
    __syncthreads();
    int cb0 = cb_dst[b], cb1 = cb_dst[b + 1];
    for (int i = cb0 + tid; i < cb1; i += 256) atomicAdd(&fine[pairs[i] & 255], 1);
    __syncthreads();
    int v = fine[tid], x = v;
#pragma unroll
    for (int d = 1; d < 64; d <<= 1) {
        int t = __shfl_up(x, d);
        if (lane >= d) x += t;
    }
    if (lane == 63) wtot[wv] = x;
    __syncthreads();
    if (tid == 0) {
        int a = 0;
#pragma unroll
        for (int k = 0; k < 4; ++k) { wexcl[k] = a; a += wtot[k]; }
    }
    __syncthreads();
    int excl = x - v + wexcl[wv];
    if (g <= N) row_ptr[g] = cb0 + excl;
    lcur[tid] = cb0 + excl;
    __syncthreads();
    for (int i = cb0 + tid; i < cb1; i += 256) {
        int p = pairs[i];
        int pos = atomicAdd(&lcur[p & 255], 1);
        col[pos] = p >> 8;
    }
}

__device__ inline void accum8(float* a, float4 raw) {
    __half2* h = (__half2*)&raw;
#pragma unroll
    for (int k = 0; k < 4; ++k) {
        float2 f = __half22float2(h[k]);
        a[2 * k] += f.x;
        a[2 * k + 1] += f.y;
    }
}

// ---- fused gather(fp16) + GEMM (+ column-sum on final layer) ----
// R12 rework: the old VGPR-resident 4-deep gather sustained only ~70 cache
// lines in flight per CU (latency-bound; VALUBusy 27%, all pipes idle).
// MLP is now decoupled from the register file via global_load_lds staging:
//   * one wave-load stages 8 src rows (64 lanes x 16B = 1KB, linear layout --
//     exactly the HW's wave-uniform-base + lane*16 write pattern)
//   * 4-edge batches, double-buffered (2 x 4KB per wave), counted
//     s_waitcnt vmcnt(4) so the next batch stays in flight (T3/T4 pattern;
//     FIFO vmcnt semantics make leftover GEMM stores in the counter safe --
//     they only make the wait conservative)
//   * col[] indices pre-staged per wave into LDS so the counted window
//     contains ONLY the 4 staging loads per batch
//   * LDS union: aggT (8x272B/wave) aliases staging buf0 (time-disjoint:
//     all gather loads drained by the final vmcnt(0) before aggT is written)
// LDS total 39936B -> still 4 blocks/CU at 128 regs (64 VGPR + 64 AGPR Wreg).
// HARD RULE (R6/R8/R11): grid <= resident capacity = 1024 blocks.
__global__ __launch_bounds__(256) void fused_kernel(const __half* __restrict__ hs_in,
                                                    const int* __restrict__ row_ptr,
                                                    const int* __restrict__ col,
                                                    const float* __restrict__ W,
                                                    const float* __restrict__ bias,
                                                    const float* __restrict__ dinv,
                                                    float* __restrict__ outf,
                                                    __half* __restrict__ outh,
                                                    float* __restrict__ msum,
                                                    int N, int mode) {
    __shared__ __align__(16) unsigned char smem[39936];
    int tid = (int)threadIdx.x;
    int lane = tid & 63;
    int wv = tid >> 6;
    int sg = lane >> 3;       // row-slot 0..7 within wave
    int q = lane & 7;         // 8 lanes per row, 16B (8 halves) each
    int g = wv * 8 + sg;      // block row 0..31

    unsigned char* wbase = smem + wv * 8192;           // staging 2x4096; aggT alias
    int* colsh = (int*)(smem + 32768 + wv * 1536);     // 384 staged col indices per wave

    float Wreg[64];
#pragma unroll
    for (int k = 0; k < 64; ++k) Wreg[k] = W[k * 64 + lane];
    float breg = bias[lane];
    float colacc = 0.0f;

    int ntiles = (N + 31) >> 5;
    for (int tile = blockIdx.x; tile < ntiles; tile += gridDim.x) {
        int node_g = tile * 32 + g;
        int beg = row_ptr[min(node_g, N)];
        int end = row_ptr[min(node_g + 1, N)];
        int deg = end - beg;                     // 0 for node_g >= N (clamped)

        int wfirst = tile * 32 + wv * 8;
        int cb = row_ptr[min(wfirst, N)];
        int ce = row_ptr[min(wfirst + 8, N)];
        int cnt = ce - cb;                       // wave's contiguous col range
        int off = beg - cb;

        int md = deg;                            // wave-max degree (groups sit on lane bits 3..5)
        md = max(md, __shfl_xor(md, 8));
        md = max(md, __shfl_xor(md, 16));
        md = max(md, __shfl_xor(md, 32));
        int rounds = (md + 3) >> 2;

        float a[8];
#pragma unroll
        for (int k = 0; k < 8; ++k) a[k] = 0.0f;

        if (cnt <= 384) {
            // stage this wave's col slice into LDS (linear lane*4 writes)
            for (int k = 0; k * 64 < cnt; ++k) {
                int i = k * 64 + lane;
                if (i < cnt) llds4(col + cb + i, (unsigned char*)colsh + k * 256);
            }
            asm volatile("s_waitcnt vmcnt(0)" ::: "memory");
            __builtin_amdgcn_sched_barrier(0);

            auto issue = [&](int b) {
                unsigned char* buf = wbase + ((b & 1) << 12);
#pragma unroll
                for (int u = 0; u < 4; ++u) {
                    int e = (b << 2) + u;
                    if (e < deg) {
                        int srcn = colsh[off + e];
                        llds16(hs_in + (size_t)srcn * D + q * 8, buf + (u << 10));
                    }
                }
            };
            if (rounds > 0) issue(0);
            if (rounds > 1) issue(1);
            for (int b = 0; b < rounds; ++b) {
                if (b + 1 < rounds) {
                    // batch b+1 (4 loads) may stay in flight; FIFO -> batch b landed
                    asm volatile("s_waitcnt vmcnt(4)" ::: "memory");
                } else {
                    asm volatile("s_waitcnt vmcnt(0)" ::: "memory");
                }
                __builtin_amdgcn_sched_barrier(0);
                unsigned char* buf = wbase + ((b & 1) << 12);
#pragma unroll
                for (int u = 0; u < 4; ++u) {
                    int e = (b << 2) + u;
                    if (e < deg) {
                        float4 raw = *(const float4*)(buf + (u << 10) + lane * 16);
                        accum8(a, raw);
                    }
                }
                if (b + 2 < rounds) issue(b + 2);   // overwrites just-consumed buffer
            }
        } else {
            // safety fallback (cnt > 384 essentially never for this graph)
            for (int j = beg; j < end; ++j) {
                int s0 = col[j];
                float4 r0 = *(const float4*)(hs_in + (size_t)s0 * D + q * 8);
                accum8(a, r0);
            }
        }

        // aggT write (aliases staging buf0 -- all gather loads drained above)
        *(float4*)(wbase + sg * 272 + q * 32) = make_float4(a[0], a[1], a[2], a[3]);
        *(float4*)(wbase + sg * 272 + q * 32 + 16) = make_float4(a[4], a[5], a[6], a[7]);

#pragma unroll
        for (int rr = 0; rr < 8; ++rr) {
            int node = tile * 32 + wv * 8 + rr;
            if (node < N) {
                float acc0 = breg, acc1 = 0.0f;
                const float4* Ar = (const float4*)(wbase + rr * 272);
#pragma unroll
                for (int k4 = 0; k4 < 16; k4 += 2) {
                    float4 av0 = Ar[k4];       // broadcast ds_read_b128, same-wave data
                    float4 av1 = Ar[k4 + 1];
                    acc0 = fmaf(av0.x, Wreg[k4 * 4 + 0], acc0);
                    acc0 = fmaf(av0.y, Wreg[k4 * 4 + 1], acc0);
                    acc0 = fmaf(av0.z, Wreg[k4 * 4 + 2], acc0);
                    acc0 = fmaf(av0.w, Wreg[k4 * 4 + 3], acc0);
                    acc1 = fmaf(av1.x, Wreg[k4 * 4 + 4], acc1);
                    acc1 = fmaf(av1.y, Wreg[k4 * 4 + 5], acc1);
                    acc1 = fmaf(av1.z, Wreg[k4 * 4 + 6], acc1);
                    acc1 = fmaf(av1.w, Wreg[k4 * 4 + 7], acc1);
                }
                float acc = acc0 + acc1;
                if (mode == 0) {
                    acc = fmaxf(acc, 0.0f) * dinv[node];
                    outh[(size_t)node * D + lane] = __float2half(acc);
                } else {
                    colacc += acc;
                    outf[(size_t)node * D + lane] = acc;
                }
            }
        }
    }

    if (mode == 1) {
        float* red = (float*)(smem + 38912);   // disjoint from colsh: waves drift!
        red[tid] = colacc;
        __syncthreads();
        if (wv == 0) {
            float s = red[lane] + red[64 + lane] + red[128 + lane] + red[192 + lane];
            atomicAdd(&msum[lane], s);
        }
    }
}

__global__ void finalize_kernel(const float* __restrict__ msum, float* __restrict__ outMean,
                                float invN) {
    outMean[threadIdx.x] = msum[threadIdx.x] * invN;
}

extern "C" void kernel_launch(void* const* d_in, const int* in_sizes, int n_in,
                              void* d_out, int out_size, void* d_ws, size_t ws_size,
                              hipStream_t stream) {
    const float* feat = (const float*)d_in[0];
    const int* src = (const int*)d_in[1];
    const int* dst = (const int*)d_in[2];
    const float* W0 = (const float*)d_in[3];
    const float* b0 = (const float*)d_in[4];
    const float* W1 = (const float*)d_in[5];
    const float* b1 = (const float*)d_in[6];
    const float* W2 = (const float*)d_in[7];
    const float* b2 = (const float*)d_in[8];

    const int N = in_sizes[0] / D;  // 100000
    const int E = in_sizes[1];      // 1600000
    float* out = (float*)d_out;     // [N*D + D] floats

    const int NBLK = (E + CHUNK - 1) / CHUNK;  // 196 <= PBSTRIDE

    // workspace layout (int units), 16B-aligned offsets; NA = padded N+1
    int* wsi = (int*)d_ws;
    const size_t NA = 100352;
    int*   row_ptr  = wsi;                       // NA
    float* dinv     = (float*)(wsi + NA);        // NA
    float* msum     = (float*)(wsi + 2 * NA);    // 64 (pad 256)
    int*   total    = wsi + 2 * NA + 256;        // 782 (pad 1024)
    int*   cb_dst   = wsi + 2 * NA + 1280;       // 392 (pad 512)
    int*   cb_src   = wsi + 2 * NA + 1792;       // 392 (pad 512)
    int*   per_blk  = wsi + 2 * NA + 2304;       // NBIN*PBSTRIDE = 200192 (pad 200704)
    int*   pairs    = wsi + 2 * NA + 203008;     // E
    unsigned char* skeys = (unsigned char*)(pairs + (size_t)E);  // E bytes (pad -> 400000 ints)
    int*   col      = pairs + (size_t)E + 400000;                // E
    __half* hsA     = (__half*)(col + (size_t)E);                // N*D halves
    __half* hsB     = hsA + (size_t)N * D;                       // N*D halves

    // (per_blk memset removed: scanA guards pad columns, phase1 fully
    //  overwrites every live column)

    phase1_kernel<<<NBLK, 256, 0, stream>>>(src, dst, per_blk, E);
    scanA_kernel<<<(NBIN + 3) / 4, 256, 0, stream>>>(per_blk, total, NBLK);
    scanB_kernel<<<1, 512, 0, stream>>>(total, cb_dst, cb_src, msum);
    phase2_kernel<<<NBLK, 256, 0, stream>>>(src, dst, per_blk, cb_dst, cb_src, pairs, skeys, E);
    finalize_csr_kernel<<<NBUK, 256, 0, stream>>>(pairs, skeys, cb_dst, cb_src, feat,
                                                  row_ptr, col, dinv, hsA, N);

    const int FG = 1024;   // == resident capacity at 4 waves/SIMD; do NOT exceed
    fused_kernel<<<FG, 256, 0, stream>>>(hsA, row_ptr, col, W0, b0, dinv, nullptr, hsB, msum, N, 0);
    fused_kernel<<<FG, 256, 0, stream>>>(hsB, row_ptr, col, W1, b1, dinv, nullptr, hsA, msum, N, 0);
    fused_kernel<<<FG, 256, 0, stream>>>(hsA, row_ptr, col, W2, b2, dinv, out, nullptr, msum, N, 1);

    finalize_kernel<<<1, 64, 0, stream>>>(msum, out + (size_t)N * D, 1.0f / (float)N);
}